// Round 4
// baseline (458.023 us; speedup 1.0000x reference)
//
#include <hip/hip_runtime.h>
#include <stdint.h>

#define NH 12
#define HD 64
#define NB 4
#define SEQ 1024
#define CDIM 768
#define MTOT (NB*SEQ)
#define MC   (MTOT*CDIM)      /* 3145728 */
#define LC   (SEQ*CDIM)       /* 786432  */
#define WSZ  (CDIM*CDIM)      /* 589824  */
#define PSZ  (NH*SEQ*SEQ)     /* 12582912 */
#define ATT_SCALE 0.125f

typedef __attribute__((ext_vector_type(4))) float f32x4;
typedef __attribute__((ext_vector_type(8))) __bf16 bf16x8;
typedef __attribute__((ext_vector_type(8))) short short8;
typedef __attribute__((ext_vector_type(4))) unsigned short ushort4v;
typedef unsigned short u16;

static __device__ __forceinline__ f32x4 mfma16(short8 a, short8 b, f32x4 c) {
  return __builtin_amdgcn_mfma_f32_16x16x32_bf16(
      __builtin_bit_cast(bf16x8, a), __builtin_bit_cast(bf16x8, b), c, 0, 0, 0);
}
static __device__ __forceinline__ u16 f2bf(float f) {
  unsigned u = __float_as_uint(f);
  u += 0x7FFFu + ((u >> 16) & 1u);
  return (u16)(u >> 16);
}
static __device__ __forceinline__ float bf2f(u16 h) {
  return __uint_as_float(((unsigned)h) << 16);
}
static __device__ __forceinline__ void lds_load16(const void* g, void* l) {
  __builtin_amdgcn_global_load_lds(
      (const __attribute__((address_space(1))) void*)g,
      (__attribute__((address_space(3))) void*)l, 16, 0, 0);
}

// ---- dtype probe over raw u16 view (fp32 data -> many extreme exponents) ----
__global__ __launch_bounds__(256) void scan_dtype(
    const u16* __restrict__ x, int n, int* __restrict__ cnt) {
  int c = 0;
  for (int i = blockIdx.x * 256 + threadIdx.x; i < n; i += gridDim.x * 256) {
    unsigned e = (x[i] >> 7) & 0xFFu;
    c += (e == 0u) | (e == 0xFFu);
  }
  if (c) atomicAdd(cnt, c);
}

// ---- dtype-adaptive convert (or copy) to bf16 ----
__global__ __launch_bounds__(256) void conv_bf16(
    const void* __restrict__ src, u16* __restrict__ dst, int n4,
    const int* __restrict__ cnt) {
  int i = blockIdx.x * 256 + threadIdx.x;
  if (i >= n4) return;
  ushort4v o;
  if (*cnt > 100) {
    f32x4 v = ((const f32x4*)src)[i];
#pragma unroll
    for (int j = 0; j < 4; j++) o[j] = f2bf(v[j]);
  } else {
    o = ((const ushort4v*)src)[i];
  }
  ((ushort4v*)dst)[i] = o;
}

// ---- prep: Xq=bf16(x+q_ape), Xk=bf16(x+k_ape), Xv=bf16(x) ----
__global__ __launch_bounds__(256) void prep_x(
    const void* __restrict__ xp, const void* __restrict__ qp,
    const void* __restrict__ kp, u16* __restrict__ Xq, u16* __restrict__ Xk,
    u16* __restrict__ Xv, const int* __restrict__ cnt) {
  int i4 = blockIdx.x * 256 + threadIdx.x;
  if (i4 * 4 >= MC) return;
  int a4 = i4 % (LC / 4);
  float xv[4], qv[4], kv[4];
  if (*cnt > 100) {
    f32x4 xx = ((const f32x4*)xp)[i4];
    f32x4 qq = ((const f32x4*)qp)[a4];
    f32x4 kk = ((const f32x4*)kp)[a4];
#pragma unroll
    for (int j = 0; j < 4; j++) { xv[j] = xx[j]; qv[j] = qq[j]; kv[j] = kk[j]; }
  } else {
    ushort4v xx = ((const ushort4v*)xp)[i4];
    ushort4v qq = ((const ushort4v*)qp)[a4];
    ushort4v kk = ((const ushort4v*)kp)[a4];
#pragma unroll
    for (int j = 0; j < 4; j++) {
      xv[j] = bf2f(xx[j]); qv[j] = bf2f(qq[j]); kv[j] = bf2f(kk[j]);
    }
  }
  ushort4v oq, ok, ov;
#pragma unroll
  for (int j = 0; j < 4; j++) {
    oq[j] = f2bf(xv[j] + qv[j]);
    ok[j] = f2bf(xv[j] + kv[j]);
    ov[j] = f2bf(xv[j]);
  }
  ((ushort4v*)Xq)[i4] = oq;
  ((ushort4v*)Xk)[i4] = ok;
  ((ushort4v*)Xv)[i4] = ov;
}

// ---- 128x128 (K=768) bf16 GEMM core: C = A · Wᵀ ----
static __device__ __forceinline__ void gemm_core(
    const u16* __restrict__ Ab, const u16* __restrict__ Wb,
    short* As, short* Bs, f32x4 acc[4][4]) {
  const int t = threadIdx.x;
  const int lane = t & 63, w = t >> 6, quad = lane >> 4, l16 = lane & 15;
  const int wm = (w >> 1) * 64, wn = (w & 1) * 64;
  const int row4 = t >> 2, chunk = (t & 3) * 8;
  for (int k0 = 0; k0 < CDIM; k0 += 32) {
    const u16* ga = Ab + row4 * CDIM + k0 + chunk;
    const u16* gb = Wb + row4 * CDIM + k0 + chunk;
    lds_load16(ga,             (char*)As + t * 16);
    lds_load16(ga + 64 * CDIM, (char*)As + 4096 + t * 16);
    lds_load16(gb,             (char*)Bs + t * 16);
    lds_load16(gb + 64 * CDIM, (char*)Bs + 4096 + t * 16);
    __syncthreads();
    short8 af[4], bw[4];
#pragma unroll
    for (int i = 0; i < 4; i++)
      af[i] = *(const short8*)(As + (wm + i * 16 + l16) * 32 + quad * 8);
#pragma unroll
    for (int j = 0; j < 4; j++)
      bw[j] = *(const short8*)(Bs + (wn + j * 16 + l16) * 32 + quad * 8);
#pragma unroll
    for (int i = 0; i < 4; i++)
#pragma unroll
      for (int j = 0; j < 4; j++)
        acc[i][j] = mfma16(af[i], bw[j], acc[i][j]);
    __syncthreads();
  }
}

// ---- QKV projections. z=0:Q z=1:K (B,H,L,D); z=2:V transposed (B,H,D,L) ----
__global__ __launch_bounds__(256) void gemm_qkv(
    const u16* __restrict__ Xq, const u16* __restrict__ Xk, const u16* __restrict__ Xv,
    const u16* __restrict__ Wq, const u16* __restrict__ Wk, const u16* __restrict__ Wv,
    u16* __restrict__ Q, u16* __restrict__ K, u16* __restrict__ Vt) {
  __shared__ __align__(16) short As[128 * 32], Bs[128 * 32];
  const int z = blockIdx.z;
  const int m0 = blockIdx.y * 128, n0 = blockIdx.x * 128;
  const u16* A = (z == 0 ? Xq : z == 1 ? Xk : Xv) + m0 * CDIM;
  const u16* W = (z == 0 ? Wq : z == 1 ? Wk : Wv) + n0 * CDIM;
  f32x4 acc[4][4];
#pragma unroll
  for (int i = 0; i < 4; i++)
#pragma unroll
    for (int j = 0; j < 4; j++) acc[i][j] = 0.f;
  gemm_core(A, W, As, Bs, acc);

  const int t = threadIdx.x, lane = t & 63, w = t >> 6;
  const int quad = lane >> 4, l16 = lane & 15;
  const int wm = (w >> 1) * 64, wn = (w & 1) * 64;
  if (z < 2) {
    u16* O = (z == 0 ? Q : K);
#pragma unroll
    for (int i = 0; i < 4; i++) {
      int mrow = m0 + wm + i * 16 + quad * 4;
      int b = mrow >> 10;
#pragma unroll
      for (int j = 0; j < 4; j++) {
        int n = n0 + wn + j * 16 + l16;
        int h = n >> 6, d = n & 63;
#pragma unroll
        for (int r = 0; r < 4; r++) {
          int l = (mrow + r) & 1023;
          O[(((b * NH + h) << 10) + l) * HD + d] = f2bf(acc[i][j][r]);
        }
      }
    }
  } else {
#pragma unroll
    for (int i = 0; i < 4; i++) {
      int l0 = m0 + wm + i * 16 + quad * 4;
      int b = l0 >> 10, l = l0 & 1023;
#pragma unroll
      for (int j = 0; j < 4; j++) {
        int n = n0 + wn + j * 16 + l16;
        int h = n >> 6, d = n & 63;
        ushort4v v;
#pragma unroll
        for (int r = 0; r < 4; r++) v[r] = f2bf(acc[i][j][r]);
        *(ushort4v*)(Vt + ((b * NH + h) * HD + d) * SEQ + l) = v;
      }
    }
  }
}

// ---- flash-style attention: 64 q-rows/block, k-tiles of 64 ----
__global__ __launch_bounds__(256) void attn(
    const u16* __restrict__ Q, const u16* __restrict__ K, const u16* __restrict__ Vt,
    const u16* __restrict__ pos, u16* __restrict__ O) {
  __shared__ __align__(16) short Ks[64 * 96], Vs[64 * 96], Ps[64 * 96];
  const int t = threadIdx.x, lane = t & 63, w = t >> 6;
  const int quad = lane >> 4, l16 = lane & 15;
  const int qt = blockIdx.x;
  const int bh = blockIdx.y;
  const int b = bh / NH, h = bh % NH;
  const int q0 = qt * 64 + w * 16;

  const u16* Qg = Q + (bh * SEQ + q0) * HD;
  short8 qa0 = *(const short8*)(Qg + l16 * HD + quad * 8);
  short8 qa1 = *(const short8*)(Qg + l16 * HD + 32 + quad * 8);

  f32x4 o[4];
#pragma unroll
  for (int j = 0; j < 4; j++) o[j] = 0.f;
  float mrow[4], lrow[4];
#pragma unroll
  for (int r = 0; r < 4; r++) { mrow[r] = -1e30f; lrow[r] = 0.f; }

  const u16* Kg = K + bh * SEQ * HD;
  const u16* Vg = Vt + bh * HD * SEQ;
  const u16* Pg = pos + (h * SEQ + q0) * SEQ;
  const int sr = t >> 3, sc = (t & 7) * 8;

  for (int kt = 0; kt < 16; kt++) {
    const int k0 = kt * 64;
    {
      const u16* kg = Kg + k0 * HD;
      *(short8*)(Ks + sr * 96 + sc)        = *(const short8*)(kg + sr * HD + sc);
      *(short8*)(Ks + (sr + 32) * 96 + sc) = *(const short8*)(kg + (sr + 32) * HD + sc);
      const u16* vg = Vg + k0;
      *(short8*)(Vs + sr * 96 + sc)        = *(const short8*)(vg + sr * SEQ + sc);
      *(short8*)(Vs + (sr + 32) * 96 + sc) = *(const short8*)(vg + (sr + 32) * SEQ + sc);
    }
    __syncthreads();

    f32x4 s[4];
#pragma unroll
    for (int j = 0; j < 4; j++) {
      short8 kb0 = *(const short8*)(Ks + (j * 16 + l16) * 96 + quad * 8);
      short8 kb1 = *(const short8*)(Ks + (j * 16 + l16) * 96 + 32 + quad * 8);
      f32x4 zz = 0.f;
      s[j] = mfma16(qa1, kb1, mfma16(qa0, kb0, zz));
    }

    float pv[4][4], mx[4];
#pragma unroll
    for (int r = 0; r < 4; r++) mx[r] = -1e30f;
#pragma unroll
    for (int j = 0; j < 4; j++)
#pragma unroll
      for (int r = 0; r < 4; r++) {
        float v = s[j][r] * ATT_SCALE +
                  bf2f(Pg[(quad * 4 + r) * SEQ + k0 + j * 16 + l16]);
        pv[j][r] = v;
        mx[r] = fmaxf(mx[r], v);
      }
#pragma unroll
    for (int off = 1; off < 16; off <<= 1)
#pragma unroll
      for (int r = 0; r < 4; r++) mx[r] = fmaxf(mx[r], __shfl_xor(mx[r], off));

    float alpha[4], rs[4];
#pragma unroll
    for (int r = 0; r < 4; r++) {
      float mnew = fmaxf(mrow[r], mx[r]);
      alpha[r] = __expf(mrow[r] - mnew);
      mrow[r] = mnew;
      rs[r] = 0.f;
    }
#pragma unroll
    for (int j = 0; j < 4; j++)
#pragma unroll
      for (int r = 0; r < 4; r++) {
        float e = __expf(pv[j][r] - mrow[r]);
        pv[j][r] = e;
        rs[r] += e;
      }
#pragma unroll
    for (int off = 1; off < 16; off <<= 1)
#pragma unroll
      for (int r = 0; r < 4; r++) rs[r] += __shfl_xor(rs[r], off);
#pragma unroll
    for (int r = 0; r < 4; r++) lrow[r] = lrow[r] * alpha[r] + rs[r];

#pragma unroll
    for (int j = 0; j < 4; j++) {
      f32x4 t4 = o[j];
#pragma unroll
      for (int r = 0; r < 4; r++) t4[r] *= alpha[r];
      o[j] = t4;
    }
    short* Pw = Ps + w * 16 * 96;
#pragma unroll
    for (int j = 0; j < 4; j++)
#pragma unroll
      for (int r = 0; r < 4; r++)
        Pw[(quad * 4 + r) * 96 + j * 16 + l16] = (short)f2bf(pv[j][r]);
    short8 pa0 = *(const short8*)(Pw + l16 * 96 + quad * 8);
    short8 pa1 = *(const short8*)(Pw + l16 * 96 + 32 + quad * 8);
#pragma unroll
    for (int j = 0; j < 4; j++) {
      short8 vb0 = *(const short8*)(Vs + (j * 16 + l16) * 96 + quad * 8);
      short8 vb1 = *(const short8*)(Vs + (j * 16 + l16) * 96 + 32 + quad * 8);
      o[j] = mfma16(pa1, vb1, mfma16(pa0, vb0, o[j]));
    }
    __syncthreads();
  }

  u16* Og = O + (b * SEQ + q0) * CDIM + h * HD;
  float inv[4];
#pragma unroll
  for (int r = 0; r < 4; r++) inv[r] = 1.0f / lrow[r];
#pragma unroll
  for (int j = 0; j < 4; j++)
#pragma unroll
    for (int r = 0; r < 4; r++)
      Og[(quad * 4 + r) * CDIM + j * 16 + l16] = f2bf(o[j][r] * inv[r]);
}

// ---- output projection + bias, FP32 output (harness reads float32) ----
__global__ __launch_bounds__(256) void gemm_proj(
    const u16* __restrict__ Oin, const u16* __restrict__ Wp,
    const u16* __restrict__ bp, float* __restrict__ out) {
  __shared__ __align__(16) short As[128 * 32], Bs[128 * 32];
  const int m0 = blockIdx.y * 128, n0 = blockIdx.x * 128;
  f32x4 acc[4][4];
#pragma unroll
  for (int i = 0; i < 4; i++)
#pragma unroll
    for (int j = 0; j < 4; j++) acc[i][j] = 0.f;
  gemm_core(Oin + m0 * CDIM, Wp + n0 * CDIM, As, Bs, acc);

  const int t = threadIdx.x, lane = t & 63, w = t >> 6;
  const int quad = lane >> 4, l16 = lane & 15;
  const int wm = (w >> 1) * 64, wn = (w & 1) * 64;
#pragma unroll
  for (int i = 0; i < 4; i++) {
    int mrow = m0 + wm + i * 16 + quad * 4;
#pragma unroll
    for (int j = 0; j < 4; j++) {
      int n = n0 + wn + j * 16 + l16;
      float bias = bf2f(bp[n]);
#pragma unroll
      for (int r = 0; r < 4; r++)
        out[(mrow + r) * CDIM + n] = acc[i][j][r] + bias;
    }
  }
}

extern "C" void kernel_launch(void* const* d_in, const int* in_sizes, int n_in,
                              void* d_out, int out_size, void* d_ws, size_t ws_size,
                              hipStream_t stream) {
  (void)out_size;
  const size_t OFF_XQ = 0, OFF_XK = (size_t)MC, OFF_XV = 2ull * MC,
               OFF_Q = 3ull * MC, OFF_K = 4ull * MC, OFF_VT = 5ull * MC,
               OFF_WQ = 6ull * MC, OFF_WK = OFF_WQ + WSZ, OFF_WV = OFF_WK + WSZ,
               OFF_WP = OFF_WV + WSZ, OFF_BP = OFF_WP + WSZ,
               OFF_POS = OFF_BP + 1024, TOT = OFF_POS + (size_t)PSZ;
  const size_t NEED = 256 + 2 * TOT;   // ~67.6 MB, proven available in R2/R3
  if (ws_size < NEED) return;

  int* cnt = (int*)d_ws;
  u16* ws = (u16*)((char*)d_ws + 256);
  u16 *Xq = ws + OFF_XQ, *Xk = ws + OFF_XK, *Xv = ws + OFF_XV;
  u16 *Qb = ws + OFF_Q, *Kb = ws + OFF_K, *Vt = ws + OFF_VT;
  u16 *Wqb = ws + OFF_WQ, *Wkb = ws + OFF_WK, *Wvb = ws + OFF_WV,
      *Wpb = ws + OFF_WP, *bpb = ws + OFF_BP, *posb = ws + OFF_POS;
  u16* Ob = Xq;  // Xq dead after gemm_qkv

  hipMemsetAsync(d_ws, 0, 256, stream);
  for (int i = 0; i < n_in && i < 9; i++)
    scan_dtype<<<256, 256, 0, stream>>>((const u16*)d_in[i], in_sizes[i], cnt);

  conv_bf16<<<PSZ / 4 / 256, 256, 0, stream>>>(d_in[3], posb, PSZ / 4, cnt);
  conv_bf16<<<WSZ / 4 / 256, 256, 0, stream>>>(d_in[4], Wqb, WSZ / 4, cnt);
  conv_bf16<<<WSZ / 4 / 256, 256, 0, stream>>>(d_in[5], Wkb, WSZ / 4, cnt);
  conv_bf16<<<WSZ / 4 / 256, 256, 0, stream>>>(d_in[6], Wvb, WSZ / 4, cnt);
  conv_bf16<<<WSZ / 4 / 256, 256, 0, stream>>>(d_in[7], Wpb, WSZ / 4, cnt);
  conv_bf16<<<1, 256, 0, stream>>>(d_in[8], bpb, CDIM / 4, cnt);
  prep_x<<<MC / 4 / 256, 256, 0, stream>>>(d_in[0], d_in[1], d_in[2],
                                           Xq, Xk, Xv, cnt);

  gemm_qkv<<<dim3(6, 32, 3), 256, 0, stream>>>(Xq, Xk, Xv, Wqb, Wkb, Wvb,
                                               Qb, Kb, Vt);
  attn<<<dim3(16, 48), 256, 0, stream>>>(Qb, Kb, Vt, posb, Ob);
  gemm_proj<<<dim3(6, 32), 256, 0, stream>>>(Ob, Wpb, bpb, (float*)d_out);
}

// Round 5
// 239.553 us; speedup vs baseline: 1.9120x; 1.9120x over previous
//
#include <hip/hip_runtime.h>
#include <stdint.h>

#define NH 12
#define HD 64
#define NB 4
#define SEQ 1024
#define CDIM 768
#define MTOT (NB*SEQ)
#define MC   (MTOT*CDIM)      /* 3145728 */
#define LC   (SEQ*CDIM)       /* 786432  */
#define WSZ  (CDIM*CDIM)      /* 589824  */
#define ATT_SCALE 0.125f

typedef __attribute__((ext_vector_type(4))) float f32x4;
typedef __attribute__((ext_vector_type(8))) __bf16 bf16x8;
typedef __attribute__((ext_vector_type(8))) short short8;
typedef __attribute__((ext_vector_type(4))) unsigned short ushort4v;
typedef unsigned short u16;

static __device__ __forceinline__ f32x4 mfma16(short8 a, short8 b, f32x4 c) {
  return __builtin_amdgcn_mfma_f32_16x16x32_bf16(
      __builtin_bit_cast(bf16x8, a), __builtin_bit_cast(bf16x8, b), c, 0, 0, 0);
}
static __device__ __forceinline__ u16 f2bf(float f) {
  unsigned u = __float_as_uint(f);
  u += 0x7FFFu + ((u >> 16) & 1u);
  return (u16)(u >> 16);
}
static __device__ __forceinline__ float bf2f(u16 h) {
  return __uint_as_float(((unsigned)h) << 16);
}
static __device__ __forceinline__ void lds_load16(const void* g, void* l) {
  __builtin_amdgcn_global_load_lds(
      (const __attribute__((address_space(1))) void*)g,
      (__attribute__((address_space(3))) void*)l, 16, 0, 0);
}

// ---- weights+bias fp32 -> bf16, single dispatch ----
__global__ __launch_bounds__(256) void conv_w(
    const float* __restrict__ Wq, const float* __restrict__ Wk,
    const float* __restrict__ Wv, const float* __restrict__ Wp,
    const float* __restrict__ bp, u16* __restrict__ dst) {
  const int N4 = (4 * WSZ + CDIM) / 4;
  int i4 = blockIdx.x * 256 + threadIdx.x;
  if (i4 >= N4) return;
  int sel = i4 / (WSZ / 4);
  int off = i4 - sel * (WSZ / 4);
  const float* src = sel == 0 ? Wq : sel == 1 ? Wk : sel == 2 ? Wv
                   : sel == 3 ? Wp : bp;
  f32x4 v = ((const f32x4*)src)[off];
  ushort4v o;
#pragma unroll
  for (int j = 0; j < 4; j++) o[j] = f2bf(v[j]);
  ((ushort4v*)dst)[i4] = o;
}

// ---- prep: Xq=bf16(x+q_ape), Xk=bf16(x+k_ape), Xv=bf16(x) — fp32 inputs ----
__global__ __launch_bounds__(256) void prep_x(
    const float* __restrict__ xp, const float* __restrict__ qp,
    const float* __restrict__ kp, u16* __restrict__ Xq, u16* __restrict__ Xk,
    u16* __restrict__ Xv) {
  int i4 = blockIdx.x * 256 + threadIdx.x;
  if (i4 * 4 >= MC) return;
  int a4 = i4 % (LC / 4);
  f32x4 xx = ((const f32x4*)xp)[i4];
  f32x4 qq = ((const f32x4*)qp)[a4];
  f32x4 kk = ((const f32x4*)kp)[a4];
  ushort4v oq, ok, ov;
#pragma unroll
  for (int j = 0; j < 4; j++) {
    oq[j] = f2bf(xx[j] + qq[j]);
    ok[j] = f2bf(xx[j] + kk[j]);
    ov[j] = f2bf(xx[j]);
  }
  ((ushort4v*)Xq)[i4] = oq;
  ((ushort4v*)Xk)[i4] = ok;
  ((ushort4v*)Xv)[i4] = ov;
}

// ---- 128x128 (K=768) bf16 GEMM core: C = A · Wᵀ ----
static __device__ __forceinline__ void gemm_core(
    const u16* __restrict__ Ab, const u16* __restrict__ Wb,
    short* As, short* Bs, f32x4 acc[4][4]) {
  const int t = threadIdx.x;
  const int lane = t & 63, w = t >> 6, quad = lane >> 4, l16 = lane & 15;
  const int wm = (w >> 1) * 64, wn = (w & 1) * 64;
  const int row4 = t >> 2, chunk = (t & 3) * 8;
  for (int k0 = 0; k0 < CDIM; k0 += 32) {
    const u16* ga = Ab + row4 * CDIM + k0 + chunk;
    const u16* gb = Wb + row4 * CDIM + k0 + chunk;
    lds_load16(ga,             (char*)As + t * 16);
    lds_load16(ga + 64 * CDIM, (char*)As + 4096 + t * 16);
    lds_load16(gb,             (char*)Bs + t * 16);
    lds_load16(gb + 64 * CDIM, (char*)Bs + 4096 + t * 16);
    __syncthreads();
    short8 af[4], bw[4];
#pragma unroll
    for (int i = 0; i < 4; i++)
      af[i] = *(const short8*)(As + (wm + i * 16 + l16) * 32 + quad * 8);
#pragma unroll
    for (int j = 0; j < 4; j++)
      bw[j] = *(const short8*)(Bs + (wn + j * 16 + l16) * 32 + quad * 8);
#pragma unroll
    for (int i = 0; i < 4; i++)
#pragma unroll
      for (int j = 0; j < 4; j++)
        acc[i][j] = mfma16(af[i], bw[j], acc[i][j]);
    __syncthreads();
  }
}

// ---- QKV projections. z=0:Q z=1:K (B,H,L,D); z=2:V transposed (B,H,D,L) ----
__global__ __launch_bounds__(256) void gemm_qkv(
    const u16* __restrict__ Xq, const u16* __restrict__ Xk, const u16* __restrict__ Xv,
    const u16* __restrict__ Wq, const u16* __restrict__ Wk, const u16* __restrict__ Wv,
    u16* __restrict__ Q, u16* __restrict__ K, u16* __restrict__ Vt) {
  __shared__ __align__(16) short As[128 * 32], Bs[128 * 32];
  const int z = blockIdx.z;
  const int m0 = blockIdx.y * 128, n0 = blockIdx.x * 128;
  const u16* A = (z == 0 ? Xq : z == 1 ? Xk : Xv) + m0 * CDIM;
  const u16* W = (z == 0 ? Wq : z == 1 ? Wk : Wv) + n0 * CDIM;
  f32x4 acc[4][4];
#pragma unroll
  for (int i = 0; i < 4; i++)
#pragma unroll
    for (int j = 0; j < 4; j++) acc[i][j] = 0.f;
  gemm_core(A, W, As, Bs, acc);

  const int t = threadIdx.x, lane = t & 63, w = t >> 6;
  const int quad = lane >> 4, l16 = lane & 15;
  const int wm = (w >> 1) * 64, wn = (w & 1) * 64;
  if (z < 2) {
    u16* O = (z == 0 ? Q : K);
#pragma unroll
    for (int i = 0; i < 4; i++) {
      int mrow = m0 + wm + i * 16 + quad * 4;
      int b = mrow >> 10;
#pragma unroll
      for (int j = 0; j < 4; j++) {
        int n = n0 + wn + j * 16 + l16;
        int h = n >> 6, d = n & 63;
#pragma unroll
        for (int r = 0; r < 4; r++) {
          int l = (mrow + r) & 1023;
          O[(((b * NH + h) << 10) + l) * HD + d] = f2bf(acc[i][j][r]);
        }
      }
    }
  } else {
#pragma unroll
    for (int i = 0; i < 4; i++) {
      int l0 = m0 + wm + i * 16 + quad * 4;
      int b = l0 >> 10, l = l0 & 1023;
#pragma unroll
      for (int j = 0; j < 4; j++) {
        int n = n0 + wn + j * 16 + l16;
        int h = n >> 6, d = n & 63;
        ushort4v v;
#pragma unroll
        for (int r = 0; r < 4; r++) v[r] = f2bf(acc[i][j][r]);
        *(ushort4v*)(Vt + ((b * NH + h) * HD + d) * SEQ + l) = v;
      }
    }
  }
}

// ---- flash-style attention: 64 q-rows/block, k-tiles of 64; pos read fp32 ----
__global__ __launch_bounds__(256) void attn(
    const u16* __restrict__ Q, const u16* __restrict__ K, const u16* __restrict__ Vt,
    const float* __restrict__ pos, u16* __restrict__ O) {
  __shared__ __align__(16) short Ks[64 * 96], Vs[64 * 96], Ps[64 * 96];
  const int t = threadIdx.x, lane = t & 63, w = t >> 6;
  const int quad = lane >> 4, l16 = lane & 15;
  const int qt = blockIdx.x;
  const int bh = blockIdx.y;
  const int b = bh / NH, h = bh % NH;
  const int q0 = qt * 64 + w * 16;

  const u16* Qg = Q + (bh * SEQ + q0) * HD;
  short8 qa0 = *(const short8*)(Qg + l16 * HD + quad * 8);
  short8 qa1 = *(const short8*)(Qg + l16 * HD + 32 + quad * 8);

  f32x4 o[4];
#pragma unroll
  for (int j = 0; j < 4; j++) o[j] = 0.f;
  float mrow[4], lrow[4];
#pragma unroll
  for (int r = 0; r < 4; r++) { mrow[r] = -1e30f; lrow[r] = 0.f; }

  const u16* Kg = K + bh * SEQ * HD;
  const u16* Vg = Vt + bh * HD * SEQ;
  const float* Pg = pos + (size_t)(h * SEQ + q0) * SEQ;
  const int sr = t >> 3, sc = (t & 7) * 8;

  for (int kt = 0; kt < 16; kt++) {
    const int k0 = kt * 64;
    {
      const u16* kg = Kg + k0 * HD;
      *(short8*)(Ks + sr * 96 + sc)        = *(const short8*)(kg + sr * HD + sc);
      *(short8*)(Ks + (sr + 32) * 96 + sc) = *(const short8*)(kg + (sr + 32) * HD + sc);
      const u16* vg = Vg + k0;
      *(short8*)(Vs + sr * 96 + sc)        = *(const short8*)(vg + sr * SEQ + sc);
      *(short8*)(Vs + (sr + 32) * 96 + sc) = *(const short8*)(vg + (sr + 32) * SEQ + sc);
    }
    __syncthreads();

    f32x4 s[4];
#pragma unroll
    for (int j = 0; j < 4; j++) {
      short8 kb0 = *(const short8*)(Ks + (j * 16 + l16) * 96 + quad * 8);
      short8 kb1 = *(const short8*)(Ks + (j * 16 + l16) * 96 + 32 + quad * 8);
      f32x4 zz = 0.f;
      s[j] = mfma16(qa1, kb1, mfma16(qa0, kb0, zz));
    }

    float pv[4][4], mx[4];
#pragma unroll
    for (int r = 0; r < 4; r++) mx[r] = -1e30f;
#pragma unroll
    for (int j = 0; j < 4; j++)
#pragma unroll
      for (int r = 0; r < 4; r++) {
        float v = s[j][r] * ATT_SCALE +
                  Pg[(quad * 4 + r) * SEQ + k0 + j * 16 + l16];
        pv[j][r] = v;
        mx[r] = fmaxf(mx[r], v);
      }
#pragma unroll
    for (int off = 1; off < 16; off <<= 1)
#pragma unroll
      for (int r = 0; r < 4; r++) mx[r] = fmaxf(mx[r], __shfl_xor(mx[r], off));

    float alpha[4], rs[4];
#pragma unroll
    for (int r = 0; r < 4; r++) {
      float mnew = fmaxf(mrow[r], mx[r]);
      alpha[r] = __expf(mrow[r] - mnew);
      mrow[r] = mnew;
      rs[r] = 0.f;
    }
#pragma unroll
    for (int j = 0; j < 4; j++)
#pragma unroll
      for (int r = 0; r < 4; r++) {
        float e = __expf(pv[j][r] - mrow[r]);
        pv[j][r] = e;
        rs[r] += e;
      }
#pragma unroll
    for (int off = 1; off < 16; off <<= 1)
#pragma unroll
      for (int r = 0; r < 4; r++) rs[r] += __shfl_xor(rs[r], off);
#pragma unroll
    for (int r = 0; r < 4; r++) lrow[r] = lrow[r] * alpha[r] + rs[r];

#pragma unroll
    for (int j = 0; j < 4; j++) {
      f32x4 t4 = o[j];
#pragma unroll
      for (int r = 0; r < 4; r++) t4[r] *= alpha[r];
      o[j] = t4;
    }
    short* Pw = Ps + w * 16 * 96;
#pragma unroll
    for (int j = 0; j < 4; j++)
#pragma unroll
      for (int r = 0; r < 4; r++)
        Pw[(quad * 4 + r) * 96 + j * 16 + l16] = (short)f2bf(pv[j][r]);
    short8 pa0 = *(const short8*)(Pw + l16 * 96 + quad * 8);
    short8 pa1 = *(const short8*)(Pw + l16 * 96 + 32 + quad * 8);
#pragma unroll
    for (int j = 0; j < 4; j++) {
      short8 vb0 = *(const short8*)(Vs + (j * 16 + l16) * 96 + quad * 8);
      short8 vb1 = *(const short8*)(Vs + (j * 16 + l16) * 96 + 32 + quad * 8);
      o[j] = mfma16(pa1, vb1, mfma16(pa0, vb0, o[j]));
    }
    __syncthreads();
  }

  u16* Og = O + (b * SEQ + q0) * CDIM + h * HD;
  float inv[4];
#pragma unroll
  for (int r = 0; r < 4; r++) inv[r] = 1.0f / lrow[r];
#pragma unroll
  for (int j = 0; j < 4; j++)
#pragma unroll
    for (int r = 0; r < 4; r++)
      Og[(quad * 4 + r) * CDIM + j * 16 + l16] = f2bf(o[j][r] * inv[r]);
}

// ---- output projection + bias, FP32 output ----
__global__ __launch_bounds__(256) void gemm_proj(
    const u16* __restrict__ Oin, const u16* __restrict__ Wp,
    const u16* __restrict__ bp, float* __restrict__ out) {
  __shared__ __align__(16) short As[128 * 32], Bs[128 * 32];
  const int m0 = blockIdx.y * 128, n0 = blockIdx.x * 128;
  f32x4 acc[4][4];
#pragma unroll
  for (int i = 0; i < 4; i++)
#pragma unroll
    for (int j = 0; j < 4; j++) acc[i][j] = 0.f;
  gemm_core(Oin + m0 * CDIM, Wp + n0 * CDIM, As, Bs, acc);

  const int t = threadIdx.x, lane = t & 63, w = t >> 6;
  const int quad = lane >> 4, l16 = lane & 15;
  const int wm = (w >> 1) * 64, wn = (w & 1) * 64;
#pragma unroll
  for (int i = 0; i < 4; i++) {
    int mrow = m0 + wm + i * 16 + quad * 4;
#pragma unroll
    for (int j = 0; j < 4; j++) {
      int n = n0 + wn + j * 16 + l16;
      float bias = bf2f(bp[n]);
#pragma unroll
      for (int r = 0; r < 4; r++)
        out[(mrow + r) * CDIM + n] = acc[i][j][r] + bias;
    }
  }
}

extern "C" void kernel_launch(void* const* d_in, const int* in_sizes, int n_in,
                              void* d_out, int out_size, void* d_ws, size_t ws_size,
                              hipStream_t stream) {
  (void)in_sizes; (void)n_in; (void)out_size;
  // ws layout (u16 elements): Xq Xk Xv | Q K Vt | Wq Wk Wv Wp bp
  const size_t OFF_XQ = 0, OFF_XK = (size_t)MC, OFF_XV = 2ull * MC,
               OFF_Q = 3ull * MC, OFF_K = 4ull * MC, OFF_VT = 5ull * MC,
               OFF_W = 6ull * MC, TOT = OFF_W + 4ull * WSZ + 1024;
  const size_t NEED = 2 * TOT;   // ~42.5 MB (67.6 proven available)
  if (ws_size < NEED) return;

  u16* ws = (u16*)d_ws;
  u16 *Xq = ws + OFF_XQ, *Xk = ws + OFF_XK, *Xv = ws + OFF_XV;
  u16 *Qb = ws + OFF_Q, *Kb = ws + OFF_K, *Vt = ws + OFF_VT;
  u16 *Wb = ws + OFF_W;
  u16 *Wqb = Wb, *Wkb = Wb + WSZ, *Wvb = Wb + 2ull * WSZ,
      *Wpb = Wb + 3ull * WSZ, *bpb = Wb + 4ull * WSZ;
  u16* Ob = Xq;  // Xq dead after gemm_qkv

  conv_w<<<(4 * WSZ + CDIM) / 4 / 256 + 1, 256, 0, stream>>>(
      (const float*)d_in[4], (const float*)d_in[5], (const float*)d_in[6],
      (const float*)d_in[7], (const float*)d_in[8], Wb);
  prep_x<<<MC / 4 / 256, 256, 0, stream>>>(
      (const float*)d_in[0], (const float*)d_in[1], (const float*)d_in[2],
      Xq, Xk, Xv);
  gemm_qkv<<<dim3(6, 32, 3), 256, 0, stream>>>(Xq, Xk, Xv, Wqb, Wkb, Wvb,
                                               Qb, Kb, Vt);
  attn<<<dim3(16, 48), 256, 0, stream>>>(Qb, Kb, Vt, (const float*)d_in[3], Ob);
  gemm_proj<<<dim3(6, 32), 256, 0, stream>>>(Ob, Wpb, bpb, (float*)d_out);
}